// Round 18
// baseline (245.031 us; speedup 1.0000x reference)
//
#include <hip/hip_runtime.h>
#include <cstdint>
#include <cstddef>

// Problem constants (MultiHeadAttention: B=4, T=2048, d_model=1024, H=16, hd=64)
#define D_MODEL 1024
#define SEQQ    2048
#define NBATCH  4
#define NHEAD   16
#define HDIM    64
#define MTOT    (NBATCH * SEQQ)   // 8192 rows

typedef __attribute__((ext_vector_type(8))) short short8;   // 8 x bf16 (4 VGPRs) — MFMA A/B frag
typedef __attribute__((ext_vector_type(4))) float floatx4;  // MFMA C/D frag
typedef unsigned short u16;                                  // bf16 bits

__device__ __forceinline__ u16 f2bf(float f) {
  union { float f; uint32_t u; } a; a.f = f;
  uint32_t u = a.u;
  u += 0x7fffu + ((u >> 16) & 1u);   // RN-even
  return (u16)(u >> 16);
}

__device__ __forceinline__ floatx4 mfma16(short8 a, short8 b, floatx4 c) {
  return __builtin_amdgcn_mfma_f32_16x16x32_bf16(a, b, c, 0, 0, 0);
}

// async global->LDS, 16B per lane. LDS dest = wave-uniform base + lane*16.
__device__ __forceinline__ void load_lds16(const void* g, void* l) {
  __builtin_amdgcn_global_load_lds(
      (const __attribute__((address_space(1))) uint32_t*)g,
      (__attribute__((address_space(3))) uint32_t*)l, 16, 0, 0);
}

// ---------------------------------------------------------------- fused casts f32->bf16
// blocks [0, 8192): X. blocks [8192, 12288): weights, 1024 blocks each.
__global__ __launch_bounds__(256) void k_cast_all(
    const float* __restrict__ X, const float* __restrict__ w0,
    const float* __restrict__ w1, const float* __restrict__ w2,
    const float* __restrict__ w3,
    u16* __restrict__ xb, u16* __restrict__ y0, u16* __restrict__ y1,
    u16* __restrict__ y2, u16* __restrict__ y3) {
  const int bx = blockIdx.x;
  const float* src; u16* dst; int i;
  if (bx < 8192) {
    src = X; dst = xb; i = (bx * 256 + threadIdx.x) * 4;
  } else {
    const int w = (bx - 8192) >> 10;
    src = (w == 0) ? w0 : (w == 1) ? w1 : (w == 2) ? w2 : w3;
    dst = (w == 0) ? y0 : (w == 1) ? y1 : (w == 2) ? y2 : y3;
    i = (((bx - 8192) & 1023) * 256 + threadIdx.x) * 4;
  }
  float4 v = *(const float4*)(src + i);
  ushort4 o;
  o.x = f2bf(v.x); o.y = f2bf(v.y); o.z = f2bf(v.z); o.w = f2bf(v.w);
  *(ushort4*)(dst + i) = o;
}

// ---------------------------------------------------------------- GEMM variant A (QKV)
// r13/r10 256-thread 4-wave kernel (QKV measured 70.4-71.7us across 3 runs).
// 2-phase dbuf + XCD remap. Untouched.
__global__ __launch_bounds__(256) void k_gemm_bt4(
    const u16* __restrict__ A,
    const u16* __restrict__ B0, const u16* __restrict__ B1, const u16* __restrict__ B2,
    void* __restrict__ C0, void* __restrict__ C1, u16* __restrict__ VtOut,
    const float* __restrict__ bias, int M, int N, int K, int f32out, float ascaleQ) {
  __shared__ __align__(16) u16 As[2][128 * 64];
  __shared__ __align__(16) u16 Bs[2][128 * 64];
  const int tid = threadIdx.x;
  const int lane = tid & 63, wave = tid >> 6;
  const int quad = lane >> 4, l15 = lane & 15;

  // XCD/L2-aware remap. 512 blocks per z.
  const int bx = blockIdx.x;
  const int swz = (bx & 7) * 64 + (bx >> 3);
  const int m0 = (swz >> 3) * 128, n0 = (swz & 7) * 128;

  const int wr = wave >> 1, wc = wave & 1;
  const u16* Bm = (blockIdx.z == 0) ? B0 : (blockIdx.z == 1 ? B1 : B2);
  void* Cm = (blockIdx.z == 0) ? C0 : C1;
  const float ascale = (blockIdx.z == 0) ? ascaleQ : 1.0f;

  floatx4 acc[4][4];
#pragma unroll
  for (int i = 0; i < 4; ++i)
#pragma unroll
    for (int jj = 0; jj < 4; ++jj) acc[i][jj] = (floatx4){0.f, 0.f, 0.f, 0.f};

  const int srow = tid >> 3;                       // 0..31
  const int scolx = ((tid & 7) * 8) ^ ((srow & 7) * 8);  // swizzled source column
  const u16* Ag = A + (size_t)(m0 + srow) * K + scolx;
  const u16* Bg = Bm + (size_t)(n0 + srow) * K + scolx;

#define STAGE_AB(tt, buf)                                                            \
  {                                                                                  \
    const int kk_ = (tt) * 64;                                                       \
    _Pragma("unroll")                                                                \
    for (int p = 0; p < 4; ++p) {                                                    \
      load_lds16(Ag + (size_t)(p * 32) * K + kk_, &As[buf][p * 2048 + wave * 512]);  \
      load_lds16(Bg + (size_t)(p * 32) * K + kk_, &Bs[buf][p * 2048 + wave * 512]);  \
    }                                                                                \
  }

  const int nIt = K / 64;   // 16
  STAGE_AB(0, 0);           // prologue: first tile in flight

  for (int it = 0; it < nIt; ++it) {
    const int cur = it & 1;
    __syncthreads();                      // drains stage(it); prior reads of buf[cur^1] done
    if (it + 1 < nIt) STAGE_AB(it + 1, cur ^ 1);   // overlaps compute(it)

    short8 af[2][4], bfg[2][4];
#pragma unroll
    for (int ks = 0; ks < 2; ++ks) {
      const int kkx = (ks * 32 + quad * 8) ^ ((l15 & 7) * 8);
#pragma unroll
      for (int i = 0; i < 4; ++i) {
        af[ks][i]  = *(const short8*)&As[cur][(wr * 64 + i * 16 + l15) * 64 + kkx];
        bfg[ks][i] = *(const short8*)&Bs[cur][(wc * 64 + i * 16 + l15) * 64 + kkx];
      }
    }
#pragma unroll
    for (int ks = 0; ks < 2; ++ks)
#pragma unroll
      for (int mi = 0; mi < 4; ++mi)
#pragma unroll
        for (int ni = 0; ni < 4; ++ni)
          acc[mi][ni] = mfma16(af[ks][mi], bfg[ks][ni], acc[mi][ni]);
  }
#undef STAGE_AB

  // Epilogue. C/D layout: col = lane&15, row = quad*4 + reg (m89-verified).
  if (blockIdx.z == 2) {
    // transposed V write: Vt[(b*16+h)*64 + d][t], 4 regs = t..t+3 contiguous
#pragma unroll
    for (int mi = 0; mi < 4; ++mi) {
#pragma unroll
      for (int ni = 0; ni < 4; ++ni) {
        const int row = m0 + wr * 64 + mi * 16 + quad * 4;   // token
        const int col = n0 + wc * 64 + ni * 16 + l15;        // channel
        const int b = row >> 11, t = row & 2047;
        const int h = col >> 6, d = col & 63;
        ushort4 pk;
        pk.x = f2bf(acc[mi][ni][0]); pk.y = f2bf(acc[mi][ni][1]);
        pk.z = f2bf(acc[mi][ni][2]); pk.w = f2bf(acc[mi][ni][3]);
        *(ushort4*)(VtOut + (((size_t)(b * 16 + h) * 64 + d) * SEQQ + t)) = pk;
      }
    }
    return;
  }
#pragma unroll
  for (int mi = 0; mi < 4; ++mi) {
#pragma unroll
    for (int ni = 0; ni < 4; ++ni) {
      const int row = m0 + wr * 64 + mi * 16 + quad * 4;
      const int col = n0 + wc * 64 + ni * 16 + l15;
      const float bv = bias ? bias[col] : 0.f;
#pragma unroll
      for (int r = 0; r < 4; ++r) {
        const float v = acc[mi][ni][r] * ascale + bv;
        if (f32out) ((float*)Cm)[(size_t)(row + r) * N + col] = v;
        else        ((u16*)Cm)[(size_t)(row + r) * N + col] = f2bf(v);
      }
    }
  }
}

// ---------------------------------------------------------------- GEMM variant B (out-proj)
// r14's 512-thread 8-wave kernel. Kept for the out-proj dispatch.
__global__ __launch_bounds__(512) void k_gemm_bt8(
    const u16* __restrict__ A, const u16* __restrict__ B0,
    float* __restrict__ Of32, const float* __restrict__ bias, int N, int K) {
  __shared__ __align__(16) u16 As[2][128 * 64];
  __shared__ __align__(16) u16 Bs[2][128 * 64];
  const int tid = threadIdx.x;
  const int lane = tid & 63, wave = tid >> 6;     // wave 0..7
  const int quad = lane >> 4, l15 = lane & 15;

  // XCD/L2-aware remap. 512 blocks.
  const int bx = blockIdx.x;
  const int swz = (bx & 7) * 64 + (bx >> 3);
  const int m0 = (swz >> 3) * 128, n0 = (swz & 7) * 128;

  const int wr = wave >> 1, wc = wave & 1;        // 4M x 2N wave grid

  floatx4 acc[2][4];
#pragma unroll
  for (int i = 0; i < 2; ++i)
#pragma unroll
    for (int jj = 0; jj < 4; ++jj) acc[i][jj] = (floatx4){0.f, 0.f, 0.f, 0.f};

  const int srow = tid >> 3;                       // 0..63 (512 threads)
  const int scolx = ((tid & 7) * 8) ^ ((srow & 7) * 8);  // swizzled source column
  const u16* Ag = A + (size_t)(m0 + srow) * K + scolx;
  const u16* Bg = B0 + (size_t)(n0 + srow) * K + scolx;

#define STAGE_AB8(tt, buf)                                                           \
  {                                                                                  \
    const int kk_ = (tt) * 64;                                                       \
    _Pragma("unroll")                                                                \
    for (int c4 = 0; c4 < 2; ++c4) {                                                 \
      load_lds16(Ag + (size_t)(c4 * 64) * K + kk_, &As[buf][c4 * 4096 + wave * 512]);\
      load_lds16(Bg + (size_t)(c4 * 64) * K + kk_, &Bs[buf][c4 * 4096 + wave * 512]);\
    }                                                                                \
  }

  const int nIt = K / 64;   // 16
  STAGE_AB8(0, 0);          // prologue: first tile in flight

  for (int it = 0; it < nIt; ++it) {
    const int cur = it & 1;
    __syncthreads();                      // drains stage(it); prior reads of buf[cur^1] done
    if (it + 1 < nIt) STAGE_AB8(it + 1, cur ^ 1);  // overlaps compute(it)

    short8 af[2][2], bfg[2][4];
#pragma unroll
    for (int ks = 0; ks < 2; ++ks) {
      const int kkx = (ks * 32 + quad * 8) ^ ((l15 & 7) * 8);
#pragma unroll
      for (int i = 0; i < 2; ++i)
        af[ks][i]  = *(const short8*)&As[cur][(wr * 32 + i * 16 + l15) * 64 + kkx];
#pragma unroll
      for (int i = 0; i < 4; ++i)
        bfg[ks][i] = *(const short8*)&Bs[cur][(wc * 64 + i * 16 + l15) * 64 + kkx];
    }
#pragma unroll
    for (int ks = 0; ks < 2; ++ks)
#pragma unroll
      for (int mi = 0; mi < 2; ++mi)
#pragma unroll
        for (int ni = 0; ni < 4; ++ni)
          acc[mi][ni] = mfma16(af[ks][mi], bfg[ks][ni], acc[mi][ni]);
  }
#undef STAGE_AB8

  // Epilogue: f32 + bias. C/D layout: col = lane&15, row = quad*4 + reg.
#pragma unroll
  for (int mi = 0; mi < 2; ++mi) {
#pragma unroll
    for (int ni = 0; ni < 4; ++ni) {
      const int row = m0 + wr * 32 + mi * 16 + quad * 4;
      const int col = n0 + wc * 64 + ni * 16 + l15;
      const float bv = bias[col];
#pragma unroll
      for (int r = 0; r < 4; ++r)
        Of32[(size_t)(row + r) * N + col] = acc[mi][ni][r] + bv;
    }
  }
}

// ---------------------------------------------------------------- flash attention
// r10 structure (4 q-tiles/wave, KVBLK=128 dbuf, permlane P-transpose, setprio).
// ROUND-18 (only change): bh-LOCALITY REMAP. Old mapping gave a CU's two
// resident blocks DIFFERENT bh (g and 32+g) and scattered the 8 same-bh blocks
// -> every block staged its K/V from HBM (FETCH 110MB vs ~34MB ideal, ~900cyc
// staging latency). New mapping: bh = c>>2, j = k2 ? 7-(c&3) : (c&3).
//  - bijective: 64 bh x (j 0..3 from k2=0, 4..7 from k2=1) = 512 blocks.
//  - balance preserved EXACTLY: CU c hosts (bh=c>>2, j=c&3) and
//    (bh=c>>2, j=7-(c&3)) -> Sum(nSub) = (32-j)+(25+j) = 57, constant.
//  - both blocks on a CU now share bh -> second block's K/V staging hits
//    L2/L1; CUs c..c+3 also share bh for further L2 reuse (topology-agnostic).
__device__ __forceinline__ short8 mk8(uint32_t a, uint32_t b, uint32_t c, uint32_t d) {
  union { uint32_t u[4]; short8 s; } t;
  t.u[0] = a; t.u[1] = b; t.u[2] = c; t.u[3] = d;
  return t.s;
}

__device__ __forceinline__ void softmax_reg(
    const floatx4 (&st)[4], float& lp, uint32_t (&w)[4][2]) {
#pragma unroll
  for (int ni = 0; ni < 4; ++ni) {
    const float p0 = __builtin_amdgcn_exp2f(st[ni][0]);
    const float p1 = __builtin_amdgcn_exp2f(st[ni][1]);
    const float p2 = __builtin_amdgcn_exp2f(st[ni][2]);
    const float p3 = __builtin_amdgcn_exp2f(st[ni][3]);
    lp += (p0 + p1) + (p2 + p3);
    w[ni][0] = __builtin_amdgcn_perm(__float_as_uint(p1), __float_as_uint(p0), 0x07060302u);
    w[ni][1] = __builtin_amdgcn_perm(__float_as_uint(p3), __float_as_uint(p2), 0x07060302u);
  }
}

// PV A-operand (keys kc*32+quad*8+{0..7} at q=l15) via quad-transpose swaps.
__device__ __forceinline__ short8 pf_prep(const uint32_t (&w)[4][2], int kc) {
  uint32_t y0 = w[2 * kc][0], z0 = w[2 * kc + 1][0];
  asm("v_permlane32_swap_b32 %0, %1" : "+v"(y0), "+v"(z0));
  asm("v_permlane16_swap_b32 %0, %1" : "+v"(y0), "+v"(z0));
  uint32_t y1 = w[2 * kc][1], z1 = w[2 * kc + 1][1];
  asm("v_permlane32_swap_b32 %0, %1" : "+v"(y1), "+v"(z1));
  asm("v_permlane16_swap_b32 %0, %1" : "+v"(y1), "+v"(z1));
  return mk8(y0, y1, z0, z1);
}

__global__ __launch_bounds__(256, 2) void k_attn(
    const u16* __restrict__ Q, const u16* __restrict__ Kg,
    const u16* __restrict__ Vt, u16* __restrict__ O) {
  __shared__ __align__(16) u16 Ks[2][128 * 64];   // [key 0..127][d 0..63]
  __shared__ __align__(16) u16 Vs[2][64 * 128];   // [d 0..63][key 0..127]
  const int tid = threadIdx.x, lane = tid & 63, wave = tid >> 6;
  const int quad = lane >> 4, l15 = lane & 15;

  // bh-locality + balance remap (see header comment)
  const int lin = blockIdx.x;
  const int c = lin & 255, k2 = lin >> 8;
  const int bh = c >> 2;                            // 0..63; shared by CU pair
  const int j = k2 ? (7 - (c & 3)) : (c & 3);       // 0..7
  const int b = bh >> 4, h = bh & 15;

  const int s = wave;                 // 16-row subtile 0..3
  const int p1 = j, p2 = j + 8;       // this block's two pairs
  int lim[4], qw[4];
  lim[0] = p1;      qw[0] = 64 * p1 + 16 * s;
  lim[1] = 31 - p1; qw[1] = SEQQ - 64 * (p1 + 1) + 16 * s;
  lim[2] = p2;      qw[2] = 64 * p2 + 16 * s;
  lim[3] = 31 - p2; qw[3] = SEQQ - 64 * (p2 + 1) + 16 * s;
  const int nSub = 32 - j;            // 64-key sub-iterations
  const int nT = (nSub + 1) >> 1;     // 128-key tiles

  const u16* kbase = Kg + (size_t)(b * SEQQ) * D_MODEL + h * HDIM;
  const u16* vbase = Vt + (size_t)bh * (HDIM * SEQQ);

  // staging (256 threads): K rows via tid>>3 (0..31, 4 calls x 32 rows);
  // V rows via tid>>4 (0..15, 4 calls x 16 rows). XOR-8 pre-swizzled source.
  const int krow = tid >> 3;
  const int kcol = ((tid & 7) * 8) ^ ((krow & 7) * 8);
  const int vrow = tid >> 4, vslot = tid & 15;
  const int vcol = (vslot >> 3) * 64 + (((vslot & 7) ^ (vrow & 7)) * 8);

#define STAGE_KV(tt, buf)                                                           \
  {                                                                                 \
    const int kt_ = (tt) * 128;                                                     \
    _Pragma("unroll")                                                               \
    for (int c4 = 0; c4 < 4; ++c4)                                                  \
      load_lds16(kbase + (size_t)(kt_ + c4 * 32 + krow) * D_MODEL + kcol,           \
                 &Ks[buf][c4 * 2048 + wave * 512]);                                 \
    _Pragma("unroll")                                                               \
    for (int c4 = 0; c4 < 4; ++c4)                                                  \
      load_lds16(vbase + (size_t)(c4 * 16 + vrow) * SEQQ + kt_ + vcol,              \
                 &Vs[buf][c4 * 2048 + wave * 512]);                                 \
  }

  STAGE_KV(0, 0);   // first tile in flight before anything else

  // Q fragments for all 4 tiles ([idx=l15][k=quad*8+jj]); Q pre-scaled.
  short8 qf[4][2];
#pragma unroll
  for (int t4 = 0; t4 < 4; ++t4) {
    const u16* qp = Q + (size_t)(b * SEQQ + qw[t4] + l15) * D_MODEL + h * HDIM;
#pragma unroll
    for (int ks = 0; ks < 2; ++ks)
      qf[t4][ks] = *(const short8*)(qp + ks * 32 + quad * 8);
  }

  floatx4 acc[4][4];
  float lp[4] = {0.f, 0.f, 0.f, 0.f};
#pragma unroll
  for (int t4 = 0; t4 < 4; ++t4)
#pragma unroll
    for (int i = 0; i < 4; ++i) acc[t4][i] = (floatx4){0.f, 0.f, 0.f, 0.f};

  for (int t = 0; t < nT; ++t) {
    const int cur = t & 1;
    __syncthreads();   // drains stage(t) (vmcnt) + all reads of buf[cur^1]
    if (t + 1 < nT) STAGE_KV(t + 1, cur ^ 1);   // overlaps compute(t)

#pragma unroll
    for (int sub = 0; sub < 2; ++sub) {
      const int u = 2 * t + sub;       // 64-key tile index

      // batched K fragment loads ([key=l15][d=quad*8+jj])
      short8 kf[4][2];
#pragma unroll
      for (int ni = 0; ni < 4; ++ni)
#pragma unroll
        for (int ks = 0; ks < 2; ++ks)
          kf[ni][ks] = *(const short8*)&Ks[cur][(sub * 64 + ni * 16 + l15) * 64 +
                                               ((ks * 32 + quad * 8) ^ ((l15 & 7) * 8))];

      uint32_t w[4][4][2];   // [tile][ni][slot]
      bool act[4];
#pragma unroll
      for (int t4 = 0; t4 < 4; ++t4) {
        act[t4] = (u <= lim[t4]);      // block-uniform
        if (act[t4]) {
          floatx4 st[4];   // S^T: row=key (quad*4+r, tile ni), col=q (l15)
          __builtin_amdgcn_s_setprio(1);
#pragma unroll
          for (int ni = 0; ni < 4; ++ni) {
            floatx4 sv = (floatx4){0.f, 0.f, 0.f, 0.f};
            sv = mfma16(kf[ni][0], qf[t4][0], sv);
            sv = mfma16(kf[ni][1], qf[t4][1], sv);
            st[ni] = sv;
          }
          __builtin_amdgcn_s_setprio(0);
          if (u == lim[t4]) {   // diagonal tile: mask key > q (position-generic)
            const int qg = qw[t4] + l15;
#pragma unroll
            for (int ni = 0; ni < 4; ++ni) {
              const int kg = u * 64 + ni * 16 + quad * 4;
#pragma unroll
              for (int r = 0; r < 4; ++r)
                if (kg + r > qg) st[ni][r] = -1e30f;
            }
          }
          softmax_reg(st, lp[t4], w[t4]);
        }
      }

      // batched V fragment loads ([d=l15][key=quad*8+jj]); shared by all tiles
      short8 vf[2][4];
#pragma unroll
      for (int kc = 0; kc < 2; ++kc)
#pragma unroll
        for (int di = 0; di < 4; ++di)
          vf[kc][di] = *(const short8*)&Vs[cur][(di * 16 + l15) * 128 + sub * 64 +
                                               ((kc * 32 + quad * 8) ^ ((l15 & 7) * 8))];

#pragma unroll
      for (int kc = 0; kc < 2; ++kc) {
#pragma unroll
        for (int t4 = 0; t4 < 4; ++t4) {
          if (act[t4]) {
            const short8 pf = pf_prep(w[t4], kc);
            __builtin_amdgcn_s_setprio(1);
#pragma unroll
            for (int di = 0; di < 4; ++di)
              acc[t4][di] = mfma16(pf, vf[kc][di], acc[t4][di]);
            __builtin_amdgcn_s_setprio(0);
          }
        }
      }
    }
  }

  // epilogue per tile: l reduce across quads, then O rows q=quad*4+r
#pragma unroll
  for (int t4 = 0; t4 < 4; ++t4) {
    float l = lp[t4];
    l += __shfl_xor(l, 16); l += __shfl_xor(l, 32);
    u16* orow = O + (size_t)(b * SEQQ + qw[t4] + quad * 4) * D_MODEL + h * HDIM + l15;
#pragma unroll
    for (int r = 0; r < 4; ++r) {
      const float inv = 1.0f / __shfl(l, quad * 4 + r, 16);
#pragma unroll
      for (int di = 0; di < 4; ++di)
        orow[(size_t)r * D_MODEL + di * 16] = f2bf(acc[t4][di][r] * inv);
    }
  }
}

// ---------------------------------------------------------------- launch
extern "C" void kernel_launch(void* const* d_in, const int* in_sizes, int n_in,
                              void* d_out, int out_size, void* d_ws, size_t ws_size,
                              hipStream_t stream) {
  const float* X  = (const float*)d_in[0];
  const float* Wq = (const float*)d_in[1];
  const float* Wk = (const float*)d_in[2];
  const float* Wv = (const float*)d_in[3];
  const float* Wo = (const float*)d_in[4];
  const float* bo = (const float*)d_in[5];
  float* out = (float*)d_out;

  u16* ws = (u16*)d_ws;
  const size_t NE = (size_t)MTOT * D_MODEL;    // 8,388,608
  u16* Xb  = ws;
  u16* Qb  = Xb + NE;
  u16* Kb  = Qb + NE;
  u16* Vt  = Kb + NE;          // V projection written directly transposed
  u16* Cb  = Vt + NE;
  u16* Wqb = Cb + NE;
  u16* Wkb = Wqb + (size_t)D_MODEL * D_MODEL;
  u16* Wvb = Wkb + (size_t)D_MODEL * D_MODEL;
  u16* Wob = Wvb + (size_t)D_MODEL * D_MODEL;

  const float SCL2E = 0.18033688f;   // (1/sqrt(64)) * log2(e), folded into Q

  // 1. all casts in one launch
  k_cast_all<<<12288, 256, 0, stream>>>(X, Wq, Wk, Wv, Wo, Xb, Wqb, Wkb, Wvb, Wob);

  // 2. fused QKV projections (Q pre-scaled; V written transposed into Vt)
  k_gemm_bt4<<<dim3(512, 1, 3), 256, 0, stream>>>(
      Xb, Wqb, Wkb, Wvb, Qb, Kb, Vt, nullptr, MTOT, D_MODEL, D_MODEL, 0, SCL2E);

  // 3. causal flash attention, bh-locality remap, balanced 1D grid
  k_attn<<<512, 256, 0, stream>>>(Qb, Kb, Vt, Cb);

  // 4. output projection + bias, f32 out (512-thread 8-wave variant)
  k_gemm_bt8<<<512, 512, 0, stream>>>(Cb, Wob, out, bo, D_MODEL, D_MODEL);
}

// Round 19
// 239.967 us; speedup vs baseline: 1.0211x; 1.0211x over previous
//
#include <hip/hip_runtime.h>
#include <cstdint>
#include <cstddef>

// Problem constants (MultiHeadAttention: B=4, T=2048, d_model=1024, H=16, hd=64)
#define D_MODEL 1024
#define SEQQ    2048
#define NBATCH  4
#define NHEAD   16
#define HDIM    64
#define MTOT    (NBATCH * SEQQ)   // 8192 rows

typedef __attribute__((ext_vector_type(8))) short short8;   // 8 x bf16 (4 VGPRs) — MFMA A/B frag
typedef __attribute__((ext_vector_type(4))) float floatx4;  // MFMA C/D frag
typedef unsigned short u16;                                  // bf16 bits

__device__ __forceinline__ u16 f2bf(float f) {
  union { float f; uint32_t u; } a; a.f = f;
  uint32_t u = a.u;
  u += 0x7fffu + ((u >> 16) & 1u);   // RN-even
  return (u16)(u >> 16);
}

__device__ __forceinline__ floatx4 mfma16(short8 a, short8 b, floatx4 c) {
  return __builtin_amdgcn_mfma_f32_16x16x32_bf16(a, b, c, 0, 0, 0);
}

// async global->LDS, 16B per lane. LDS dest = wave-uniform base + lane*16.
__device__ __forceinline__ void load_lds16(const void* g, void* l) {
  __builtin_amdgcn_global_load_lds(
      (const __attribute__((address_space(1))) uint32_t*)g,
      (__attribute__((address_space(3))) uint32_t*)l, 16, 0, 0);
}

// ---------------------------------------------------------------- fused casts f32->bf16
// blocks [0, 8192): X. blocks [8192, 12288): weights, 1024 blocks each.
__global__ __launch_bounds__(256) void k_cast_all(
    const float* __restrict__ X, const float* __restrict__ w0,
    const float* __restrict__ w1, const float* __restrict__ w2,
    const float* __restrict__ w3,
    u16* __restrict__ xb, u16* __restrict__ y0, u16* __restrict__ y1,
    u16* __restrict__ y2, u16* __restrict__ y3) {
  const int bx = blockIdx.x;
  const float* src; u16* dst; int i;
  if (bx < 8192) {
    src = X; dst = xb; i = (bx * 256 + threadIdx.x) * 4;
  } else {
    const int w = (bx - 8192) >> 10;
    src = (w == 0) ? w0 : (w == 1) ? w1 : (w == 2) ? w2 : w3;
    dst = (w == 0) ? y0 : (w == 1) ? y1 : (w == 2) ? y2 : y3;
    i = (((bx - 8192) & 1023) * 256 + threadIdx.x) * 4;
  }
  float4 v = *(const float4*)(src + i);
  ushort4 o;
  o.x = f2bf(v.x); o.y = f2bf(v.y); o.z = f2bf(v.z); o.w = f2bf(v.w);
  *(ushort4*)(dst + i) = o;
}

// ---------------------------------------------------------------- GEMM variant A (QKV)
// r13/r10 256-thread 4-wave kernel (QKV measured 70.4-71.7us across 4 runs).
// 2-phase dbuf + XCD remap. ROUND-19: exact restore of the r17 session-best
// config (240.1us). r18's attn bh-locality remap regressed (+5us: same-bh
// blocks on consecutive CUs land on different XCDs under round-robin dispatch
// -> no L2 sharing, plus same-channel HBM burst contention). Reverted.
__global__ __launch_bounds__(256) void k_gemm_bt4(
    const u16* __restrict__ A,
    const u16* __restrict__ B0, const u16* __restrict__ B1, const u16* __restrict__ B2,
    void* __restrict__ C0, void* __restrict__ C1, u16* __restrict__ VtOut,
    const float* __restrict__ bias, int M, int N, int K, int f32out, float ascaleQ) {
  __shared__ __align__(16) u16 As[2][128 * 64];
  __shared__ __align__(16) u16 Bs[2][128 * 64];
  const int tid = threadIdx.x;
  const int lane = tid & 63, wave = tid >> 6;
  const int quad = lane >> 4, l15 = lane & 15;

  // XCD/L2-aware remap. 512 blocks per z.
  const int bx = blockIdx.x;
  const int swz = (bx & 7) * 64 + (bx >> 3);
  const int m0 = (swz >> 3) * 128, n0 = (swz & 7) * 128;

  const int wr = wave >> 1, wc = wave & 1;
  const u16* Bm = (blockIdx.z == 0) ? B0 : (blockIdx.z == 1 ? B1 : B2);
  void* Cm = (blockIdx.z == 0) ? C0 : C1;
  const float ascale = (blockIdx.z == 0) ? ascaleQ : 1.0f;

  floatx4 acc[4][4];
#pragma unroll
  for (int i = 0; i < 4; ++i)
#pragma unroll
    for (int jj = 0; jj < 4; ++jj) acc[i][jj] = (floatx4){0.f, 0.f, 0.f, 0.f};

  const int srow = tid >> 3;                       // 0..31
  const int scolx = ((tid & 7) * 8) ^ ((srow & 7) * 8);  // swizzled source column
  const u16* Ag = A + (size_t)(m0 + srow) * K + scolx;
  const u16* Bg = Bm + (size_t)(n0 + srow) * K + scolx;

#define STAGE_AB(tt, buf)                                                            \
  {                                                                                  \
    const int kk_ = (tt) * 64;                                                       \
    _Pragma("unroll")                                                                \
    for (int p = 0; p < 4; ++p) {                                                    \
      load_lds16(Ag + (size_t)(p * 32) * K + kk_, &As[buf][p * 2048 + wave * 512]);  \
      load_lds16(Bg + (size_t)(p * 32) * K + kk_, &Bs[buf][p * 2048 + wave * 512]);  \
    }                                                                                \
  }

  const int nIt = K / 64;   // 16
  STAGE_AB(0, 0);           // prologue: first tile in flight

  for (int it = 0; it < nIt; ++it) {
    const int cur = it & 1;
    __syncthreads();                      // drains stage(it); prior reads of buf[cur^1] done
    if (it + 1 < nIt) STAGE_AB(it + 1, cur ^ 1);   // overlaps compute(it)

    short8 af[2][4], bfg[2][4];
#pragma unroll
    for (int ks = 0; ks < 2; ++ks) {
      const int kkx = (ks * 32 + quad * 8) ^ ((l15 & 7) * 8);
#pragma unroll
      for (int i = 0; i < 4; ++i) {
        af[ks][i]  = *(const short8*)&As[cur][(wr * 64 + i * 16 + l15) * 64 + kkx];
        bfg[ks][i] = *(const short8*)&Bs[cur][(wc * 64 + i * 16 + l15) * 64 + kkx];
      }
    }
#pragma unroll
    for (int ks = 0; ks < 2; ++ks)
#pragma unroll
      for (int mi = 0; mi < 4; ++mi)
#pragma unroll
        for (int ni = 0; ni < 4; ++ni)
          acc[mi][ni] = mfma16(af[ks][mi], bfg[ks][ni], acc[mi][ni]);
  }
#undef STAGE_AB

  // Epilogue. C/D layout: col = lane&15, row = quad*4 + reg (m89-verified).
  if (blockIdx.z == 2) {
    // transposed V write: Vt[(b*16+h)*64 + d][t], 4 regs = t..t+3 contiguous
#pragma unroll
    for (int mi = 0; mi < 4; ++mi) {
#pragma unroll
      for (int ni = 0; ni < 4; ++ni) {
        const int row = m0 + wr * 64 + mi * 16 + quad * 4;   // token
        const int col = n0 + wc * 64 + ni * 16 + l15;        // channel
        const int b = row >> 11, t = row & 2047;
        const int h = col >> 6, d = col & 63;
        ushort4 pk;
        pk.x = f2bf(acc[mi][ni][0]); pk.y = f2bf(acc[mi][ni][1]);
        pk.z = f2bf(acc[mi][ni][2]); pk.w = f2bf(acc[mi][ni][3]);
        *(ushort4*)(VtOut + (((size_t)(b * 16 + h) * 64 + d) * SEQQ + t)) = pk;
      }
    }
    return;
  }
#pragma unroll
  for (int mi = 0; mi < 4; ++mi) {
#pragma unroll
    for (int ni = 0; ni < 4; ++ni) {
      const int row = m0 + wr * 64 + mi * 16 + quad * 4;
      const int col = n0 + wc * 64 + ni * 16 + l15;
      const float bv = bias ? bias[col] : 0.f;
#pragma unroll
      for (int r = 0; r < 4; ++r) {
        const float v = acc[mi][ni][r] * ascale + bv;
        if (f32out) ((float*)Cm)[(size_t)(row + r) * N + col] = v;
        else        ((u16*)Cm)[(size_t)(row + r) * N + col] = f2bf(v);
      }
    }
  }
}

// ---------------------------------------------------------------- GEMM variant B (out-proj)
// r14's 512-thread 8-wave kernel. Kept for the out-proj dispatch.
__global__ __launch_bounds__(512) void k_gemm_bt8(
    const u16* __restrict__ A, const u16* __restrict__ B0,
    float* __restrict__ Of32, const float* __restrict__ bias, int N, int K) {
  __shared__ __align__(16) u16 As[2][128 * 64];
  __shared__ __align__(16) u16 Bs[2][128 * 64];
  const int tid = threadIdx.x;
  const int lane = tid & 63, wave = tid >> 6;     // wave 0..7
  const int quad = lane >> 4, l15 = lane & 15;

  // XCD/L2-aware remap. 512 blocks.
  const int bx = blockIdx.x;
  const int swz = (bx & 7) * 64 + (bx >> 3);
  const int m0 = (swz >> 3) * 128, n0 = (swz & 7) * 128;

  const int wr = wave >> 1, wc = wave & 1;        // 4M x 2N wave grid

  floatx4 acc[2][4];
#pragma unroll
  for (int i = 0; i < 2; ++i)
#pragma unroll
    for (int jj = 0; jj < 4; ++jj) acc[i][jj] = (floatx4){0.f, 0.f, 0.f, 0.f};

  const int srow = tid >> 3;                       // 0..63 (512 threads)
  const int scolx = ((tid & 7) * 8) ^ ((srow & 7) * 8);  // swizzled source column
  const u16* Ag = A + (size_t)(m0 + srow) * K + scolx;
  const u16* Bg = B0 + (size_t)(n0 + srow) * K + scolx;

#define STAGE_AB8(tt, buf)                                                           \
  {                                                                                  \
    const int kk_ = (tt) * 64;                                                       \
    _Pragma("unroll")                                                                \
    for (int c4 = 0; c4 < 2; ++c4) {                                                 \
      load_lds16(Ag + (size_t)(c4 * 64) * K + kk_, &As[buf][c4 * 4096 + wave * 512]);\
      load_lds16(Bg + (size_t)(c4 * 64) * K + kk_, &Bs[buf][c4 * 4096 + wave * 512]);\
    }                                                                                \
  }

  const int nIt = K / 64;   // 16
  STAGE_AB8(0, 0);          // prologue: first tile in flight

  for (int it = 0; it < nIt; ++it) {
    const int cur = it & 1;
    __syncthreads();                      // drains stage(it); prior reads of buf[cur^1] done
    if (it + 1 < nIt) STAGE_AB8(it + 1, cur ^ 1);  // overlaps compute(it)

    short8 af[2][2], bfg[2][4];
#pragma unroll
    for (int ks = 0; ks < 2; ++ks) {
      const int kkx = (ks * 32 + quad * 8) ^ ((l15 & 7) * 8);
#pragma unroll
      for (int i = 0; i < 2; ++i)
        af[ks][i]  = *(const short8*)&As[cur][(wr * 32 + i * 16 + l15) * 64 + kkx];
#pragma unroll
      for (int i = 0; i < 4; ++i)
        bfg[ks][i] = *(const short8*)&Bs[cur][(wc * 64 + i * 16 + l15) * 64 + kkx];
    }
#pragma unroll
    for (int ks = 0; ks < 2; ++ks)
#pragma unroll
      for (int mi = 0; mi < 2; ++mi)
#pragma unroll
        for (int ni = 0; ni < 4; ++ni)
          acc[mi][ni] = mfma16(af[ks][mi], bfg[ks][ni], acc[mi][ni]);
  }
#undef STAGE_AB8

  // Epilogue: f32 + bias. C/D layout: col = lane&15, row = quad*4 + reg.
#pragma unroll
  for (int mi = 0; mi < 2; ++mi) {
#pragma unroll
    for (int ni = 0; ni < 4; ++ni) {
      const int row = m0 + wr * 32 + mi * 16 + quad * 4;
      const int col = n0 + wc * 64 + ni * 16 + l15;
      const float bv = bias[col];
#pragma unroll
      for (int r = 0; r < 4; ++r)
        Of32[(size_t)(row + r) * N + col] = acc[mi][ni][r] + bv;
    }
  }
}

// ---------------------------------------------------------------- flash attention
// r10 structure (4 q-tiles/wave, KVBLK=128 dbuf with Vs in LDS, permlane
// P-transpose, setprio, original balanced grid mapping) — session best.
__device__ __forceinline__ short8 mk8(uint32_t a, uint32_t b, uint32_t c, uint32_t d) {
  union { uint32_t u[4]; short8 s; } t;
  t.u[0] = a; t.u[1] = b; t.u[2] = c; t.u[3] = d;
  return t.s;
}

__device__ __forceinline__ void softmax_reg(
    const floatx4 (&st)[4], float& lp, uint32_t (&w)[4][2]) {
#pragma unroll
  for (int ni = 0; ni < 4; ++ni) {
    const float p0 = __builtin_amdgcn_exp2f(st[ni][0]);
    const float p1 = __builtin_amdgcn_exp2f(st[ni][1]);
    const float p2 = __builtin_amdgcn_exp2f(st[ni][2]);
    const float p3 = __builtin_amdgcn_exp2f(st[ni][3]);
    lp += (p0 + p1) + (p2 + p3);
    w[ni][0] = __builtin_amdgcn_perm(__float_as_uint(p1), __float_as_uint(p0), 0x07060302u);
    w[ni][1] = __builtin_amdgcn_perm(__float_as_uint(p3), __float_as_uint(p2), 0x07060302u);
  }
}

// PV A-operand (keys kc*32+quad*8+{0..7} at q=l15) via quad-transpose swaps.
__device__ __forceinline__ short8 pf_prep(const uint32_t (&w)[4][2], int kc) {
  uint32_t y0 = w[2 * kc][0], z0 = w[2 * kc + 1][0];
  asm("v_permlane32_swap_b32 %0, %1" : "+v"(y0), "+v"(z0));
  asm("v_permlane16_swap_b32 %0, %1" : "+v"(y0), "+v"(z0));
  uint32_t y1 = w[2 * kc][1], z1 = w[2 * kc + 1][1];
  asm("v_permlane32_swap_b32 %0, %1" : "+v"(y1), "+v"(z1));
  asm("v_permlane16_swap_b32 %0, %1" : "+v"(y1), "+v"(z1));
  return mk8(y0, y1, z0, z1);
}

__global__ __launch_bounds__(256, 2) void k_attn(
    const u16* __restrict__ Q, const u16* __restrict__ Kg,
    const u16* __restrict__ Vt, u16* __restrict__ O) {
  __shared__ __align__(16) u16 Ks[2][128 * 64];   // [key 0..127][d 0..63]
  __shared__ __align__(16) u16 Vs[2][64 * 128];   // [d 0..63][key 0..127]
  const int tid = threadIdx.x, lane = tid & 63, wave = tid >> 6;
  const int quad = lane >> 4, l15 = lane & 15;

  // balanced (j, bh): CU c hosts blocks c and c+256 -> j and 7-j
  // -> per-CU Sum(nSub) = (32-j)+(25+j) = 57, constant.
  const int lin = blockIdx.x;
  const int c = lin & 255, k2 = lin >> 8;
  const int j = k2 ? (7 - (c & 7)) : (c & 7);       // 0..7
  const int bh = (c >> 3) | (k2 << 5);              // 0..63
  const int b = bh >> 4, h = bh & 15;

  const int s = wave;                 // 16-row subtile 0..3
  const int p1 = j, p2 = j + 8;       // this block's two pairs
  int lim[4], qw[4];
  lim[0] = p1;      qw[0] = 64 * p1 + 16 * s;
  lim[1] = 31 - p1; qw[1] = SEQQ - 64 * (p1 + 1) + 16 * s;
  lim[2] = p2;      qw[2] = 64 * p2 + 16 * s;
  lim[3] = 31 - p2; qw[3] = SEQQ - 64 * (p2 + 1) + 16 * s;
  const int nSub = 32 - j;            // 64-key sub-iterations
  const int nT = (nSub + 1) >> 1;     // 128-key tiles

  const u16* kbase = Kg + (size_t)(b * SEQQ) * D_MODEL + h * HDIM;
  const u16* vbase = Vt + (size_t)bh * (HDIM * SEQQ);

  // staging (256 threads): K rows via tid>>3 (0..31, 4 calls x 32 rows);
  // V rows via tid>>4 (0..15, 4 calls x 16 rows). XOR-8 pre-swizzled source.
  const int krow = tid >> 3;
  const int kcol = ((tid & 7) * 8) ^ ((krow & 7) * 8);
  const int vrow = tid >> 4, vslot = tid & 15;
  const int vcol = (vslot >> 3) * 64 + (((vslot & 7) ^ (vrow & 7)) * 8);

#define STAGE_KV(tt, buf)                                                           \
  {                                                                                 \
    const int kt_ = (tt) * 128;                                                     \
    _Pragma("unroll")                                                               \
    for (int c4 = 0; c4 < 4; ++c4)                                                  \
      load_lds16(kbase + (size_t)(kt_ + c4 * 32 + krow) * D_MODEL + kcol,           \
                 &Ks[buf][c4 * 2048 + wave * 512]);                                 \
    _Pragma("unroll")                                                               \
    for (int c4 = 0; c4 < 4; ++c4)                                                  \
      load_lds16(vbase + (size_t)(c4 * 16 + vrow) * SEQQ + kt_ + vcol,              \
                 &Vs[buf][c4 * 2048 + wave * 512]);                                 \
  }

  STAGE_KV(0, 0);   // first tile in flight before anything else

  // Q fragments for all 4 tiles ([idx=l15][k=quad*8+jj]); Q pre-scaled.
  short8 qf[4][2];
#pragma unroll
  for (int t4 = 0; t4 < 4; ++t4) {
    const u16* qp = Q + (size_t)(b * SEQQ + qw[t4] + l15) * D_MODEL + h * HDIM;
#pragma unroll
    for (int ks = 0; ks < 2; ++ks)
      qf[t4][ks] = *(const short8*)(qp + ks * 32 + quad * 8);
  }

  floatx4 acc[4][4];
  float lp[4] = {0.f, 0.f, 0.f, 0.f};
#pragma unroll
  for (int t4 = 0; t4 < 4; ++t4)
#pragma unroll
    for (int i = 0; i < 4; ++i) acc[t4][i] = (floatx4){0.f, 0.f, 0.f, 0.f};

  for (int t = 0; t < nT; ++t) {
    const int cur = t & 1;
    __syncthreads();   // drains stage(t) (vmcnt) + all reads of buf[cur^1]
    if (t + 1 < nT) STAGE_KV(t + 1, cur ^ 1);   // overlaps compute(t)

#pragma unroll
    for (int sub = 0; sub < 2; ++sub) {
      const int u = 2 * t + sub;       // 64-key tile index

      // batched K fragment loads ([key=l15][d=quad*8+jj])
      short8 kf[4][2];
#pragma unroll
      for (int ni = 0; ni < 4; ++ni)
#pragma unroll
        for (int ks = 0; ks < 2; ++ks)
          kf[ni][ks] = *(const short8*)&Ks[cur][(sub * 64 + ni * 16 + l15) * 64 +
                                               ((ks * 32 + quad * 8) ^ ((l15 & 7) * 8))];

      uint32_t w[4][4][2];   // [tile][ni][slot]
      bool act[4];
#pragma unroll
      for (int t4 = 0; t4 < 4; ++t4) {
        act[t4] = (u <= lim[t4]);      // block-uniform
        if (act[t4]) {
          floatx4 st[4];   // S^T: row=key (quad*4+r, tile ni), col=q (l15)
          __builtin_amdgcn_s_setprio(1);
#pragma unroll
          for (int ni = 0; ni < 4; ++ni) {
            floatx4 sv = (floatx4){0.f, 0.f, 0.f, 0.f};
            sv = mfma16(kf[ni][0], qf[t4][0], sv);
            sv = mfma16(kf[ni][1], qf[t4][1], sv);
            st[ni] = sv;
          }
          __builtin_amdgcn_s_setprio(0);
          if (u == lim[t4]) {   // diagonal tile: mask key > q (position-generic)
            const int qg = qw[t4] + l15;
#pragma unroll
            for (int ni = 0; ni < 4; ++ni) {
              const int kg = u * 64 + ni * 16 + quad * 4;
#pragma unroll
              for (int r = 0; r < 4; ++r)
                if (kg + r > qg) st[ni][r] = -1e30f;
            }
          }
          softmax_reg(st, lp[t4], w[t4]);
        }
      }

      // batched V fragment loads ([d=l15][key=quad*8+jj]); shared by all tiles
      short8 vf[2][4];
#pragma unroll
      for (int kc = 0; kc < 2; ++kc)
#pragma unroll
        for (int di = 0; di < 4; ++di)
          vf[kc][di] = *(const short8*)&Vs[cur][(di * 16 + l15) * 128 + sub * 64 +
                                               ((kc * 32 + quad * 8) ^ ((l15 & 7) * 8))];

#pragma unroll
      for (int kc = 0; kc < 2; ++kc) {
#pragma unroll
        for (int t4 = 0; t4 < 4; ++t4) {
          if (act[t4]) {
            const short8 pf = pf_prep(w[t4], kc);
            __builtin_amdgcn_s_setprio(1);
#pragma unroll
            for (int di = 0; di < 4; ++di)
              acc[t4][di] = mfma16(pf, vf[kc][di], acc[t4][di]);
            __builtin_amdgcn_s_setprio(0);
          }
        }
      }
    }
  }

  // epilogue per tile: l reduce across quads, then O rows q=quad*4+r
#pragma unroll
  for (int t4 = 0; t4 < 4; ++t4) {
    float l = lp[t4];
    l += __shfl_xor(l, 16); l += __shfl_xor(l, 32);
    u16* orow = O + (size_t)(b * SEQQ + qw[t4] + quad * 4) * D_MODEL + h * HDIM + l15;
#pragma unroll
    for (int r = 0; r < 4; ++r) {
      const float inv = 1.0f / __shfl(l, quad * 4 + r, 16);
#pragma unroll
      for (int di = 0; di < 4; ++di)
        orow[(size_t)r * D_MODEL + di * 16] = f2bf(acc[t4][di][r] * inv);
    }
  }
}

// ---------------------------------------------------------------- launch
extern "C" void kernel_launch(void* const* d_in, const int* in_sizes, int n_in,
                              void* d_out, int out_size, void* d_ws, size_t ws_size,
                              hipStream_t stream) {
  const float* X  = (const float*)d_in[0];
  const float* Wq = (const float*)d_in[1];
  const float* Wk = (const float*)d_in[2];
  const float* Wv = (const float*)d_in[3];
  const float* Wo = (const float*)d_in[4];
  const float* bo = (const float*)d_in[5];
  float* out = (float*)d_out;

  u16* ws = (u16*)d_ws;
  const size_t NE = (size_t)MTOT * D_MODEL;    // 8,388,608
  u16* Xb  = ws;
  u16* Qb  = Xb + NE;
  u16* Kb  = Qb + NE;
  u16* Vt  = Kb + NE;          // V projection written directly transposed
  u16* Cb  = Vt + NE;
  u16* Wqb = Cb + NE;
  u16* Wkb = Wqb + (size_t)D_MODEL * D_MODEL;
  u16* Wvb = Wkb + (size_t)D_MODEL * D_MODEL;
  u16* Wob = Wvb + (size_t)D_MODEL * D_MODEL;

  const float SCL2E = 0.18033688f;   // (1/sqrt(64)) * log2(e), folded into Q

  // 1. all casts in one launch
  k_cast_all<<<12288, 256, 0, stream>>>(X, Wq, Wk, Wv, Wo, Xb, Wqb, Wkb, Wvb, Wob);

  // 2. fused QKV projections (Q pre-scaled; V written transposed into Vt)
  k_gemm_bt4<<<dim3(512, 1, 3), 256, 0, stream>>>(
      Xb, Wqb, Wkb, Wvb, Qb, Kb, Vt, nullptr, MTOT, D_MODEL, D_MODEL, 0, SCL2E);

  // 3. causal flash attention, 4 q-tiles/wave, Vs-in-LDS, balanced 1D grid
  k_attn<<<512, 256, 0, stream>>>(Qb, Kb, Vt, Cb);

  // 4. output projection + bias, f32 out (512-thread 8-wave variant)
  k_gemm_bt8<<<512, 512, 0, stream>>>(Cb, Wob, out, bo, D_MODEL, D_MODEL);
}